// Round 5
// baseline (116.453 us; speedup 1.0000x reference)
//
#include <hip/hip_runtime.h>
#include <hip/hip_bf16.h>

// ---------------- problem constants ----------------
#define NIMG 16
#define CIN 128
#define COUT 256
#define HH 64
#define WW 64
#define KHE 7
#define KW_ 3
#define HP (HH + 6)   // 70
#define WP (WW + 2)   // 66
#define KDIM (CIN * KHE * KW_)  // 2688
#define NKT 42                  // K-tiles of 64

typedef __attribute__((ext_vector_type(8))) short short8;
typedef __attribute__((ext_vector_type(4))) float f32x4;
typedef __attribute__((ext_vector_type(16))) float f32x16;

#define AS1(p) ((const __attribute__((address_space(1))) void*)(p))
#define AS3(p) ((__attribute__((address_space(3))) void*)(p))

// ---------------- kernel 1: pad + NCHW->NHWC transpose + f32->bf16 ----------------
__global__ void __launch_bounds__(256) pad_convert(const float* __restrict__ x,
                                                   ushort* __restrict__ xp) {
  const int bid = blockIdx.x;          // 16*70
  const int n = bid / HP, hp = bid % HP;
  const int h = hp - 3;
  ushort* dst = xp + (size_t)(n * HP + hp) * (WP * CIN);
  const int tid = threadIdx.x;

  if (h < 0 || h >= HH) {
    uint4* p = (uint4*)dst;
    uint4 z; z.x = z.y = z.z = z.w = 0u;
    for (int idx = tid; idx < (WP * CIN * 2) / 16; idx += 256) p[idx] = z;
    return;
  }

  __shared__ ushort t[CIN][WW + 1];
  for (int it = 0; it < (CIN * WW) / 256; ++it) {
    int flat = it * 256 + tid;
    int i = flat >> 6, w = flat & 63;
    float v = x[(((size_t)n * CIN + i) * HH + h) * WW + w];
    __hip_bfloat16 b = __float2bfloat16(v);
    t[i][w] = *(ushort*)&b;
  }
  __syncthreads();
  for (int it = 0; it < (WP * CIN) / 256; ++it) {
    int flat = it * 256 + tid;
    int wp = flat >> 7, i = flat & 127;
    int w = wp - 1;
    ushort v = (w < 0 || w >= WW) ? (ushort)0 : t[i][w];
    dst[flat] = v;
  }
}

// ---------------- kernel 2: build dense bf16 kernel, layout [k/8][o][8] ----------------
// global k = (kh_eff*3+kw)*128 + i ; ks = k>>3 ; kb2[ks*2048 + o*8 + (k&7)]
__global__ void __launch_bounds__(256) build_kb(const float* __restrict__ weight,
                                                const float* __restrict__ P,
                                                ushort* __restrict__ kb2) {
  int idx = blockIdx.x * 256 + threadIdx.x;
  if (idx >= COUT * KW_ * CIN) return;
  int i = idx & 127;
  int kw = (idx >> 7) % 3;
  int o = idx / (KW_ * CIN);
  int base = (o * CIN + i) * 9 + kw;

  float a[KHE] = {0.f, 0.f, 0.f, 0.f, 0.f, 0.f, 0.f};
#pragma unroll
  for (int kh = 0; kh < 3; ++kh) {
    float wv = weight[base + kh * 3];
    float p = P[base + kh * 3];
    p = fminf(2.f, fmaxf(-2.f, p));
    float pos = (float)(kh + 2) + p;
    float fl = floorf(pos);
    float fr = pos - fl;
    int r0 = (int)fl;
    float c0 = wv * (1.f - fr);
    float c1 = wv * fr;
#pragma unroll
    for (int r = 0; r < KHE; ++r) {
      a[r] += ((r0 == r) ? c0 : 0.f) + ((r0 + 1 == r) ? c1 : 0.f);
    }
  }
#pragma unroll
  for (int r = 0; r < KHE; ++r) {
    __hip_bfloat16 b = __float2bfloat16(a[r]);
    int ks = (r * 3 + kw) * 16 + (i >> 3);
    kb2[(size_t)ks * 2048 + o * 8 + (i & 7)] = *(ushort*)&b;
  }
}

// ---------------- kernel 3: implicit-GEMM conv, 32x32x16 MFMA, 4-buf A, 1 barrier/tile ----------------
// M = 65536, N = 256, K = 2688 = 42 x 64. 8 waves (2M x 4N), per-wave 128x64.
// LDS A layout per 32KB buffer: offset = (kchunk*256 + row)*16B, kchunk = within-tile k/8.
__global__ void __launch_bounds__(512, 2) dcls_gemm(const ushort* __restrict__ xp,
                                                    const ushort* __restrict__ kb2,
                                                    const float* __restrict__ bias,
                                                    float* __restrict__ out) {
  __shared__ __align__(16) ushort As[4][16384];   // 128 KiB

  const int tid = threadIdx.x;
  const int lane = tid & 63;
  const int wv = tid >> 6;       // 0..7 (also the staged k-chunk owner)
  const int wr = wv >> 2;        // 0..1 along M
  const int wc = wv & 3;         // 0..3 along N
  const int m0 = blockIdx.x << 8;

  // stage source: instr j covers rows j*64+lane of the M-tile, k-chunk wv (8 elems)
  const ushort* pA[4];
#pragma unroll
  for (int j = 0; j < 4; ++j) {
    int m = m0 + j * 64 + lane;
    int ni = m >> 12, hh = (m >> 6) & 63, ww = m & 63;
    pA[j] = xp + (size_t)((ni * HP + hh) * WP + ww) * CIN + wv * 8;
  }
  // B frag source: elem addr = (kt*8 + kk*2 + (lane>>5))*2048 + (wc*64 + nf*32 + (lane&31))*8
  const ushort* kbB = kb2 + (size_t)(lane >> 5) * 2048 + (size_t)(wc * 64 + (lane & 31)) * 8;

#define STAGEA(buf, kt) do { \
    int kh_ = (kt) / 6, rem_ = (kt) - kh_ * 6, kw2_ = rem_ >> 1, ic_ = rem_ & 1; \
    int offA_ = (kh_ * WP + kw2_) * CIN + ic_ * 64; \
    _Pragma("unroll") \
    for (int j_ = 0; j_ < 4; ++j_) \
      __builtin_amdgcn_global_load_lds(AS1(pA[j_] + offA_), \
          AS3((char*)&As[buf][0] + wv * 4096 + j_ * 1024), 16, 0, 0); \
  } while (0)

#define LOADB(dst, kt) do { \
    _Pragma("unroll") \
    for (int n_ = 0; n_ < 2; ++n_) \
      _Pragma("unroll") \
      for (int kk_ = 0; kk_ < 4; ++kk_) \
        dst[n_][kk_] = *(const short8*)(kbB + ((size_t)((kt) * 8 + kk_ * 2) * 2048 + n_ * 256)); \
  } while (0)

  f32x16 acc[4][2] = {};
  short8 bf0[2][4], bf1[2][4];

#define TILE_MFMA(buf, bfc) do { \
    const char* Ab = (const char*)&As[buf][0]; \
    _Pragma("unroll") \
    for (int mf_ = 0; mf_ < 4; ++mf_) { \
      short8 af[4]; \
      _Pragma("unroll") \
      for (int kk_ = 0; kk_ < 4; ++kk_) \
        af[kk_] = *(const short8*)(Ab + kk_ * 8192 + (lane >> 5) * 4096 + \
                                   (wr * 128 + mf_ * 32 + (lane & 31)) * 16); \
      _Pragma("unroll") \
      for (int kk_ = 0; kk_ < 4; ++kk_) \
        _Pragma("unroll") \
        for (int n_ = 0; n_ < 2; ++n_) \
          acc[mf_][n_] = __builtin_amdgcn_mfma_f32_32x32x16_bf16( \
              af[kk_], bfc[n_][kk_], acc[mf_][n_], 0, 0, 0); \
    } \
  } while (0)

  // one tile: wait own A(kt)+B(kt) landed (oldest 12), barrier, then issue
  // next-next stage up front and compute; B prefetch after its WAR clears.
#define SUBITER(kt, bfc) do { \
    __builtin_amdgcn_sched_barrier(0); \
    asm volatile("s_waitcnt vmcnt(12)" ::: "memory"); \
    __builtin_amdgcn_s_barrier(); \
    __builtin_amdgcn_sched_barrier(0); \
    { int ktn_ = ((kt) + 2 < NKT) ? (kt) + 2 : 0; \
      STAGEA(((kt) + 2) & 3, ktn_); \
      TILE_MFMA((kt) & 3, bfc); \
      LOADB(bfc, ktn_); } \
  } while (0)

  // prologue: A0,B0,A1,B1 -> 24 outstanding
  STAGEA(0, 0);
  LOADB(bf0, 0);
  STAGEA(1, 1);
  LOADB(bf1, 1);

  for (int kt = 0; kt < NKT; kt += 2) {
    SUBITER(kt, bf0);
    SUBITER(kt + 1, bf1);
  }
#undef SUBITER
#undef TILE_MFMA
#undef LOADB
#undef STAGEA

  // keep tail prefetches alive (vmcnt-count integrity under unroll+DCE)
#pragma unroll
  for (int n_ = 0; n_ < 2; ++n_)
#pragma unroll
    for (int kk_ = 0; kk_ < 4; ++kk_) {
      asm volatile("" :: "v"((int)bf0[n_][kk_][0]));
      asm volatile("" :: "v"((int)bf1[n_][kk_][0]));
    }

  // epilogue: 32x32 C/D layout col(o)=lane&31, row(m)=(reg&3)+8*(reg>>2)+4*(lane>>5)
#pragma unroll
  for (int nf = 0; nf < 2; ++nf) {
    int o = wc * 64 + nf * 32 + (lane & 31);
    float bv = bias[o];
#pragma unroll
    for (int mf = 0; mf < 4; ++mf) {
#pragma unroll
      for (int q = 0; q < 4; ++q) {
        int m = m0 + wr * 128 + mf * 32 + q * 8 + (lane >> 5) * 4;
        int ni = m >> 12, hh = (m >> 6) & 63, ww = m & 63;
        f32x4 v;
        v[0] = acc[mf][nf][q * 4 + 0] + bv;
        v[1] = acc[mf][nf][q * 4 + 1] + bv;
        v[2] = acc[mf][nf][q * 4 + 2] + bv;
        v[3] = acc[mf][nf][q * 4 + 3] + bv;
        *(f32x4*)(out + (size_t)((ni * COUT + o) * HH + hh) * WW + ww) = v;
      }
    }
  }
}

// ---------------- launcher ----------------
extern "C" void kernel_launch(void* const* d_in, const int* in_sizes, int n_in,
                              void* d_out, int out_size, void* d_ws, size_t ws_size,
                              hipStream_t stream) {
  const float* x = (const float*)d_in[0];
  const float* weight = (const float*)d_in[1];
  const float* bias = (const float*)d_in[2];
  const float* P = (const float*)d_in[3];
  float* out = (float*)d_out;

  const size_t xp_elems = (size_t)NIMG * HP * WP * CIN;
  ushort* xp = (ushort*)d_ws;
  ushort* kb2 = (ushort*)((char*)d_ws + xp_elems * 2);

  hipLaunchKernelGGL(pad_convert, dim3(NIMG * HP), dim3(256), 0, stream, x, xp);
  hipLaunchKernelGGL(build_kb, dim3((COUT * KW_ * CIN + 255) / 256), dim3(256), 0, stream,
                     weight, P, kb2);
  hipLaunchKernelGGL(dcls_gemm, dim3(65536 / 256), dim3(512), 0, stream, xp, kb2, bias, out);
}

// Round 6
// 96.742 us; speedup vs baseline: 1.2038x; 1.2038x over previous
//
#include <hip/hip_runtime.h>
#include <hip/hip_bf16.h>

// ---------------- problem constants ----------------
#define NIMG 16
#define CIN 128
#define COUT 256
#define HH 64
#define WW 64
#define KHE 7
#define KW_ 3
#define HP (HH + 6)   // 70
#define WP (WW + 2)   // 66
#define KDIM (CIN * KHE * KW_)  // 2688
#define NKT 42                  // K-tiles of 64

typedef __attribute__((ext_vector_type(8))) short short8;
typedef __attribute__((ext_vector_type(4))) float f32x4;

#define AS1(p) ((const __attribute__((address_space(1))) void*)(p))
#define AS3(p) ((__attribute__((address_space(3))) void*)(p))

// ---------------- kernel 1: pad + NCHW->NHWC transpose + f32->bf16 ----------------
__global__ void __launch_bounds__(256) pad_convert(const float* __restrict__ x,
                                                   ushort* __restrict__ xp) {
  const int bid = blockIdx.x;          // 16*70
  const int n = bid / HP, hp = bid % HP;
  const int h = hp - 3;
  ushort* dst = xp + (size_t)(n * HP + hp) * (WP * CIN);
  const int tid = threadIdx.x;

  if (h < 0 || h >= HH) {
    uint4* p = (uint4*)dst;
    uint4 z; z.x = z.y = z.z = z.w = 0u;
    for (int idx = tid; idx < (WP * CIN * 2) / 16; idx += 256) p[idx] = z;
    return;
  }

  __shared__ ushort t[CIN][WW + 1];
  for (int it = 0; it < (CIN * WW) / 256; ++it) {
    int flat = it * 256 + tid;
    int i = flat >> 6, w = flat & 63;
    float v = x[(((size_t)n * CIN + i) * HH + h) * WW + w];
    __hip_bfloat16 b = __float2bfloat16(v);
    t[i][w] = *(ushort*)&b;
  }
  __syncthreads();
  for (int it = 0; it < (WP * CIN) / 256; ++it) {
    int flat = it * 256 + tid;
    int wp = flat >> 7, i = flat & 127;
    int w = wp - 1;
    ushort v = (w < 0 || w >= WW) ? (ushort)0 : t[i][w];
    dst[flat] = v;
  }
}

// ---------------- kernel 2: build dense bf16 kernel in MFMA-fragment order ----------------
// kb2[kslice][o][32] where kslice = (kh_eff*3+kw)*4 + (i>>5), within-slice = i&31.
__global__ void __launch_bounds__(256) build_kb(const float* __restrict__ weight,
                                                const float* __restrict__ P,
                                                ushort* __restrict__ kb2) {
  int idx = blockIdx.x * 256 + threadIdx.x;
  if (idx >= COUT * KW_ * CIN) return;
  int i = idx & 127;
  int kw = (idx >> 7) % 3;
  int o = idx / (KW_ * CIN);
  int base = (o * CIN + i) * 9 + kw;

  float a[KHE] = {0.f, 0.f, 0.f, 0.f, 0.f, 0.f, 0.f};
#pragma unroll
  for (int kh = 0; kh < 3; ++kh) {
    float wv = weight[base + kh * 3];
    float p = P[base + kh * 3];
    p = fminf(2.f, fmaxf(-2.f, p));
    float pos = (float)(kh + 2) + p;
    float fl = floorf(pos);
    float fr = pos - fl;
    int r0 = (int)fl;
    float c0 = wv * (1.f - fr);
    float c1 = wv * fr;
#pragma unroll
    for (int r = 0; r < KHE; ++r) {
      a[r] += ((r0 == r) ? c0 : 0.f) + ((r0 + 1 == r) ? c1 : 0.f);
    }
  }
#pragma unroll
  for (int r = 0; r < KHE; ++r) {
    __hip_bfloat16 b = __float2bfloat16(a[r]);
    int kslice = (r * 3 + kw) * 4 + (i >> 5);
    kb2[(size_t)kslice * 8192 + o * 32 + (i & 31)] = *(ushort*)&b;
  }
}

// ---------------- kernel 3: implicit-GEMM conv; A via 4-buf LDS, B via L2->regs ----------------
// M = 65536, N = 256 (one tile), K = 2688 = 42 x 64
// 8 waves (2M x 4N), per-wave output 128x64, acc = 32 x f32x4. ONE barrier per K-tile.
__global__ void __launch_bounds__(512, 2) dcls_gemm(const ushort* __restrict__ xp,
                                                    const ushort* __restrict__ kb2,
                                                    const float* __restrict__ bias,
                                                    float* __restrict__ out) {
  __shared__ __align__(16) ushort As[4][256 * 64];   // 128 KiB

  const int tid = threadIdx.x;
  const int lane = tid & 63;
  const int wv = tid >> 6;       // 0..7
  const int wr = wv >> 2;        // 0..1 along M
  const int wc = wv & 3;         // 0..3 along N
  const int g = lane >> 4;
  const int lm = lane & 15;
  const int m0 = blockIdx.x << 8;

  // A staging: 512 threads x 16B, source pre-swizzled (rule #21)
  const int srow = tid >> 3;
  const int swz = ((tid & 7) ^ (srow & 7)) * 8;

  const ushort* pA[4];
#pragma unroll
  for (int j = 0; j < 4; ++j) {
    int r = j * 64 + srow;
    int m = m0 + r;
    int ni = m >> 12, hh = (m >> 6) & 63, ww = m & 63;
    pA[j] = xp + (size_t)((ni * HP + hh) * WP + ww) * CIN + swz;
  }

  // B fragment base: lane part of ((kslice*256 + o)*32 + g*8)
  const ushort* kbB = kb2 + (size_t)wc * 2048 + lm * 32 + g * 8;

#define STAGEA(buf, kt) do { \
    int kh_ = (kt) / 6; int rem_ = (kt) - kh_ * 6; \
    int kw2_ = rem_ >> 1; int ic_ = rem_ & 1; \
    int offA_ = (kh_ * WP + kw2_) * CIN + ic_ * 64; \
    _Pragma("unroll") \
    for (int j_ = 0; j_ < 4; ++j_) \
      __builtin_amdgcn_global_load_lds(AS1(pA[j_] + offA_), AS3(&As[buf][(j_ * 64 + wv * 8) * 64]), 16, 0, 0); \
  } while (0)

#define LOADB(dst, kt) do { \
    _Pragma("unroll") \
    for (int n_ = 0; n_ < 4; ++n_) \
      _Pragma("unroll") \
      for (int kk_ = 0; kk_ < 2; ++kk_) \
        dst[n_][kk_] = *(const short8*)(kbB + (size_t)((kt) * 2 + kk_) * 8192 + n_ * 512); \
  } while (0)

  f32x4 acc[8][4] = {};
  const int swzR = (lm & 7) << 4;

  short8 bf0[4][2], bf1[4][2];

  // compute body for one K-tile: A-frags from As[buf], B from bf (in regs)
#define TILE_MFMA(buf, bf) do { \
    const char* Ab = (const char*)&As[buf][0]; \
    _Pragma("unroll") \
    for (int half_ = 0; half_ < 2; ++half_) { \
      short8 af[4][2]; \
      _Pragma("unroll") \
      for (int m4_ = 0; m4_ < 4; ++m4_) \
        _Pragma("unroll") \
        for (int kk_ = 0; kk_ < 2; ++kk_) { \
          int rowA_ = wr * 128 + half_ * 64 + m4_ * 16 + lm; \
          af[m4_][kk_] = *(const short8*)(Ab + rowA_ * 128 + ((kk_ * 64 + g * 16) ^ swzR)); \
        } \
      _Pragma("unroll") \
      for (int kk_ = 0; kk_ < 2; ++kk_) \
        _Pragma("unroll") \
        for (int m4_ = 0; m4_ < 4; ++m4_) \
          _Pragma("unroll") \
          for (int n_ = 0; n_ < 4; ++n_) \
            acc[half_ * 4 + m4_][n_] = __builtin_amdgcn_mfma_f32_16x16x32_bf16( \
                af[m4_][kk_], bf[n_][kk_], acc[half_ * 4 + m4_][n_], 0, 0, 0); \
    } \
  } while (0)

  // one K-tile, ONE barrier: wait own A(kt)+B(kt) (oldest 12 of 24), barrier,
  // immediately re-issue stage for kt+2 (free buffer, no WAR), compute,
  // then prefetch B(kt+2) once bfc's WAR clears.
#define SUBITER(kt, bfc) do { \
    __builtin_amdgcn_sched_barrier(0); \
    asm volatile("s_waitcnt vmcnt(12)" ::: "memory"); \
    __builtin_amdgcn_s_barrier(); \
    __builtin_amdgcn_sched_barrier(0); \
    { int ktn_ = ((kt) + 2 < NKT) ? (kt) + 2 : 0; \
      STAGEA(((kt) + 2) & 3, ktn_); \
      TILE_MFMA((kt) & 3, bfc); \
      LOADB(bfc, ktn_); } \
  } while (0)

  // prologue: A0,B0,A1,B1 -> 24 outstanding
  STAGEA(0, 0);
  LOADB(bf0, 0);
  STAGEA(1, 1);
  LOADB(bf1, 1);

  for (int kt = 0; kt < NKT; kt += 2) {
    SUBITER(kt, bf0);
    SUBITER(kt + 1, bf1);
  }
#undef SUBITER
#undef TILE_MFMA
#undef LOADB
#undef STAGEA

  // keep tail prefetches alive (vmcnt-count integrity under unroll+DCE)
#pragma unroll
  for (int n_ = 0; n_ < 4; ++n_)
#pragma unroll
    for (int kk_ = 0; kk_ < 2; ++kk_) {
      asm volatile("" :: "v"((int)bf0[n_][kk_][0]));
      asm volatile("" :: "v"((int)bf1[n_][kk_][0]));
    }

  // epilogue: C/D layout col(o)=lane&15, row(m)=(lane>>4)*4+reg; fuse bias
#pragma unroll
  for (int fn = 0; fn < 4; ++fn) {
    int o = wc * 64 + fn * 16 + lm;
    float bv = bias[o];
#pragma unroll
    for (int fm = 0; fm < 8; ++fm) {
      int m = m0 + wr * 128 + fm * 16 + g * 4;
      int ni = m >> 12, hh = (m >> 6) & 63, ww = m & 63;
      f32x4 v = acc[fm][fn];
      v[0] += bv; v[1] += bv; v[2] += bv; v[3] += bv;
      *(f32x4*)(out + (size_t)((ni * COUT + o) * HH + hh) * WW + ww) = v;
    }
  }
}

// ---------------- launcher ----------------
extern "C" void kernel_launch(void* const* d_in, const int* in_sizes, int n_in,
                              void* d_out, int out_size, void* d_ws, size_t ws_size,
                              hipStream_t stream) {
  const float* x = (const float*)d_in[0];
  const float* weight = (const float*)d_in[1];
  const float* bias = (const float*)d_in[2];
  const float* P = (const float*)d_in[3];
  float* out = (float*)d_out;

  const size_t xp_elems = (size_t)NIMG * HP * WP * CIN;
  ushort* xp = (ushort*)d_ws;
  ushort* kb2 = (ushort*)((char*)d_ws + xp_elems * 2);

  hipLaunchKernelGGL(pad_convert, dim3(NIMG * HP), dim3(256), 0, stream, x, xp);
  hipLaunchKernelGGL(build_kb, dim3((COUT * KW_ * CIN + 255) / 256), dim3(256), 0, stream,
                     weight, P, kb2);
  hipLaunchKernelGGL(dcls_gemm, dim3(65536 / 256), dim3(512), 0, stream, xp, kb2, bias, out);
}

// Round 7
// 96.072 us; speedup vs baseline: 1.2121x; 1.0070x over previous
//
#include <hip/hip_runtime.h>
#include <hip/hip_bf16.h>

// ---------------- problem constants ----------------
#define NIMG 16
#define CIN 128
#define COUT 256
#define HH 64
#define WW 64
#define KHE 7
#define KW_ 3
#define HP (HH + 6)   // 70
#define WP (WW + 2)   // 66
#define KDIM (CIN * KHE * KW_)  // 2688
#define NKT 42                  // K-tiles of 64

typedef __attribute__((ext_vector_type(8))) short short8;
typedef __attribute__((ext_vector_type(4))) float f32x4;

#define AS1(p) ((const __attribute__((address_space(1))) void*)(p))
#define AS3(p) ((__attribute__((address_space(3))) void*)(p))

// ---------------- kernel 1: pad + NCHW->NHWC transpose + f32->bf16 ----------------
__global__ void __launch_bounds__(256) pad_convert(const float* __restrict__ x,
                                                   ushort* __restrict__ xp) {
  const int bid = blockIdx.x;          // 16*70
  const int n = bid / HP, hp = bid % HP;
  const int h = hp - 3;
  ushort* dst = xp + (size_t)(n * HP + hp) * (WP * CIN);
  const int tid = threadIdx.x;

  if (h < 0 || h >= HH) {
    uint4* p = (uint4*)dst;
    uint4 z; z.x = z.y = z.z = z.w = 0u;
    for (int idx = tid; idx < (WP * CIN * 2) / 16; idx += 256) p[idx] = z;
    return;
  }

  __shared__ ushort t[CIN][WW + 1];
  for (int it = 0; it < (CIN * WW) / 256; ++it) {
    int flat = it * 256 + tid;
    int i = flat >> 6, w = flat & 63;
    float v = x[(((size_t)n * CIN + i) * HH + h) * WW + w];
    __hip_bfloat16 b = __float2bfloat16(v);
    t[i][w] = *(ushort*)&b;
  }
  __syncthreads();
  for (int it = 0; it < (WP * CIN) / 256; ++it) {
    int flat = it * 256 + tid;
    int wp = flat >> 7, i = flat & 127;
    int w = wp - 1;
    ushort v = (w < 0 || w >= WW) ? (ushort)0 : t[i][w];
    dst[flat] = v;
  }
}

// ---------------- kernel 2: build dense bf16 kernel in MFMA-fragment order ----------------
// kb2[kslice][o][32] where kslice = (kh_eff*3+kw)*4 + (i>>5), within-slice = i&31.
__global__ void __launch_bounds__(256) build_kb(const float* __restrict__ weight,
                                                const float* __restrict__ P,
                                                ushort* __restrict__ kb2) {
  int idx = blockIdx.x * 256 + threadIdx.x;
  if (idx >= COUT * KW_ * CIN) return;
  int i = idx & 127;
  int kw = (idx >> 7) % 3;
  int o = idx / (KW_ * CIN);
  int base = (o * CIN + i) * 9 + kw;

  float a[KHE] = {0.f, 0.f, 0.f, 0.f, 0.f, 0.f, 0.f};
#pragma unroll
  for (int kh = 0; kh < 3; ++kh) {
    float wv = weight[base + kh * 3];
    float p = P[base + kh * 3];
    p = fminf(2.f, fmaxf(-2.f, p));
    float pos = (float)(kh + 2) + p;
    float fl = floorf(pos);
    float fr = pos - fl;
    int r0 = (int)fl;
    float c0 = wv * (1.f - fr);
    float c1 = wv * fr;
#pragma unroll
    for (int r = 0; r < KHE; ++r) {
      a[r] += ((r0 == r) ? c0 : 0.f) + ((r0 + 1 == r) ? c1 : 0.f);
    }
  }
#pragma unroll
  for (int r = 0; r < KHE; ++r) {
    __hip_bfloat16 b = __float2bfloat16(a[r]);
    int kslice = (r * 3 + kw) * 4 + (i >> 5);
    kb2[(size_t)kslice * 8192 + o * 32 + (i & 31)] = *(ushort*)&b;
  }
}

// ---------------- kernel 3: implicit-GEMM conv; A via 4-buf LDS, B via L2->regs ----------------
// M = 65536, N = 256 (one tile), K = 2688 = 42 x 64
// 8 waves (2M x 4N), per-wave output 128x64. ONE barrier per K-tile.
// In-wave 4-group pipeline: ds_reads of group p+1 issue under MFMAs of group p
// (counted lgkmcnt; DS completes in order).
__global__ void __launch_bounds__(512, 2) dcls_gemm(const ushort* __restrict__ xp,
                                                    const ushort* __restrict__ kb2,
                                                    const float* __restrict__ bias,
                                                    float* __restrict__ out) {
  __shared__ __align__(16) ushort As[4][256 * 64];   // 128 KiB

  const int tid = threadIdx.x;
  const int lane = tid & 63;
  const int wv = tid >> 6;       // 0..7
  const int wr = wv >> 2;        // 0..1 along M
  const int wc = wv & 3;         // 0..3 along N
  const int g = lane >> 4;
  const int lm = lane & 15;
  const int m0 = blockIdx.x << 8;

  // A staging: 512 threads x 16B, source pre-swizzled (rule #21)
  const int srow = tid >> 3;
  const int swz = ((tid & 7) ^ (srow & 7)) * 8;

  const ushort* pA[4];
#pragma unroll
  for (int j = 0; j < 4; ++j) {
    int r = j * 64 + srow;
    int m = m0 + r;
    int ni = m >> 12, hh = (m >> 6) & 63, ww = m & 63;
    pA[j] = xp + (size_t)((ni * HP + hh) * WP + ww) * CIN + swz;
  }

  // B fragment base: lane part of ((kslice*256 + o)*32 + g*8)
  const ushort* kbB = kb2 + (size_t)wc * 2048 + lm * 32 + g * 8;

#define STAGEA(buf, kt) do { \
    int kh_ = (kt) / 6; int rem_ = (kt) - kh_ * 6; \
    int kw2_ = rem_ >> 1; int ic_ = rem_ & 1; \
    int offA_ = (kh_ * WP + kw2_) * CIN + ic_ * 64; \
    _Pragma("unroll") \
    for (int j_ = 0; j_ < 4; ++j_) \
      __builtin_amdgcn_global_load_lds(AS1(pA[j_] + offA_), AS3(&As[buf][(j_ * 64 + wv * 8) * 64]), 16, 0, 0); \
  } while (0)

#define LOADB(dst, kt) do { \
    _Pragma("unroll") \
    for (int n_ = 0; n_ < 4; ++n_) \
      _Pragma("unroll") \
      for (int kk_ = 0; kk_ < 2; ++kk_) \
        dst[n_][kk_] = *(const short8*)(kbB + (size_t)((kt) * 2 + kk_) * 8192 + n_ * 512); \
  } while (0)

  f32x4 acc[8][4] = {};
  const int swzR = (lm & 7) << 4;

  short8 bf0[4][2], bf1[4][2];
  short8 afp[4], afq[4];   // ping-pong read groups (static names, rule #20)

  // 4 ds_read_b128 of one (half,kk) fragment group
#define READ_AF(dst, Ab, half, kk) do { \
    _Pragma("unroll") \
    for (int m4_ = 0; m4_ < 4; ++m4_) { \
      int rowA_ = wr * 128 + (half) * 64 + m4_ * 16 + lm; \
      dst[m4_] = *(const short8*)((Ab) + rowA_ * 128 + (((kk) * 64 + g * 16) ^ swzR)); \
    } \
  } while (0)

  // 16 MFMA consuming one fragment group
#define MFMA_G(afv, bfc, half, kk) do { \
    __builtin_amdgcn_s_setprio(1); \
    _Pragma("unroll") \
    for (int m4_ = 0; m4_ < 4; ++m4_) \
      _Pragma("unroll") \
      for (int n_ = 0; n_ < 4; ++n_) \
        acc[(half) * 4 + m4_][n_] = __builtin_amdgcn_mfma_f32_16x16x32_bf16( \
            afv[m4_], bfc[n_][kk], acc[(half) * 4 + m4_][n_], 0, 0, 0); \
    __builtin_amdgcn_s_setprio(0); \
  } while (0)

#define LGKM_GATE(n) do { \
    __builtin_amdgcn_sched_barrier(0); \
    asm volatile("s_waitcnt lgkmcnt(" #n ")" ::: "memory"); \
    __builtin_amdgcn_sched_barrier(0); \
  } while (0)

  // one K-tile, ONE barrier, 4-stage in-wave pipeline
#define SUBITER(kt, bfc) do { \
    __builtin_amdgcn_sched_barrier(0); \
    asm volatile("s_waitcnt vmcnt(12)" ::: "memory"); \
    __builtin_amdgcn_s_barrier(); \
    __builtin_amdgcn_sched_barrier(0); \
    int ktn_ = ((kt) + 2 < NKT) ? (kt) + 2 : 0; \
    STAGEA(((kt) + 2) & 3, ktn_); \
    const char* Ab = (const char*)&As[(kt) & 3][0]; \
    READ_AF(afp, Ab, 0, 0); \
    READ_AF(afq, Ab, 0, 1); \
    LGKM_GATE(4); \
    MFMA_G(afp, bfc, 0, 0); \
    READ_AF(afp, Ab, 1, 0); \
    LGKM_GATE(4); \
    MFMA_G(afq, bfc, 0, 1); \
    READ_AF(afq, Ab, 1, 1); \
    LGKM_GATE(4); \
    MFMA_G(afp, bfc, 1, 0); \
    LGKM_GATE(0); \
    MFMA_G(afq, bfc, 1, 1); \
    LOADB(bfc, ktn_); \
  } while (0)

  // prologue: A0,B0,A1,B1 -> 24 outstanding
  STAGEA(0, 0);
  LOADB(bf0, 0);
  STAGEA(1, 1);
  LOADB(bf1, 1);

  for (int kt = 0; kt < NKT; kt += 2) {
    SUBITER(kt, bf0);
    SUBITER(kt + 1, bf1);
  }
#undef SUBITER
#undef LGKM_GATE
#undef MFMA_G
#undef READ_AF
#undef LOADB
#undef STAGEA

  // keep tail prefetches alive (vmcnt-count integrity under unroll+DCE)
#pragma unroll
  for (int n_ = 0; n_ < 4; ++n_)
#pragma unroll
    for (int kk_ = 0; kk_ < 2; ++kk_) {
      asm volatile("" :: "v"((int)bf0[n_][kk_][0]));
      asm volatile("" :: "v"((int)bf1[n_][kk_][0]));
    }

  // epilogue: C/D layout col(o)=lane&15, row(m)=(lane>>4)*4+reg; fuse bias
#pragma unroll
  for (int fn = 0; fn < 4; ++fn) {
    int o = wc * 64 + fn * 16 + lm;
    float bv = bias[o];
#pragma unroll
    for (int fm = 0; fm < 8; ++fm) {
      int m = m0 + wr * 128 + fm * 16 + g * 4;
      int ni = m >> 12, hh = (m >> 6) & 63, ww = m & 63;
      f32x4 v = acc[fm][fn];
      v[0] += bv; v[1] += bv; v[2] += bv; v[3] += bv;
      *(f32x4*)(out + (size_t)((ni * COUT + o) * HH + hh) * WW + ww) = v;
    }
  }
}

// ---------------- launcher ----------------
extern "C" void kernel_launch(void* const* d_in, const int* in_sizes, int n_in,
                              void* d_out, int out_size, void* d_ws, size_t ws_size,
                              hipStream_t stream) {
  const float* x = (const float*)d_in[0];
  const float* weight = (const float*)d_in[1];
  const float* bias = (const float*)d_in[2];
  const float* P = (const float*)d_in[3];
  float* out = (float*)d_out;

  const size_t xp_elems = (size_t)NIMG * HP * WP * CIN;
  ushort* xp = (ushort*)d_ws;
  ushort* kb2 = (ushort*)((char*)d_ws + xp_elems * 2);

  hipLaunchKernelGGL(pad_convert, dim3(NIMG * HP), dim3(256), 0, stream, x, xp);
  hipLaunchKernelGGL(build_kb, dim3((COUT * KW_ * CIN + 255) / 256), dim3(256), 0, stream,
                     weight, P, kb2);
  hipLaunchKernelGGL(dcls_gemm, dim3(65536 / 256), dim3(512), 0, stream, xp, kb2, bias, out);
}